// Round 11
// baseline (1873.136 us; speedup 1.0000x reference)
//
#include <hip/hip_runtime.h>
#include <hip/hip_bf16.h>
#include <math.h>

// ---------------- bucketed CSR build (R9 config — known good) ----------------
// bucket = dst >> 8 (256 nodes/bucket). NB = ceil(N/256) <= 512.
// R6: single-pass random 4B scatter caused 16x write amplification -> two-level
// counting sort. R10's re-chunk (2048-edge chunks, 1024 buckets) REGRESSED
// ~+20 us (LDS init/flush + global-atomic overhead per tiny chunk): reverted.

#define CSR_CHUNK 8192

__global__ void k_bhist(const int* __restrict__ dst, int* __restrict__ bcount,
                        int E, int NB) {
    __shared__ int h[512];
    int t = threadIdx.x;
    for (int i = t; i < NB; i += 256) h[i] = 0;
    __syncthreads();
    int e0 = blockIdx.x * CSR_CHUNK;
    int e1 = min(e0 + CSR_CHUNK, E);
    for (int i = e0 + t; i < e1; i += 256) atomicAdd(&h[dst[i] >> 8], 1);
    __syncthreads();
    for (int i = t; i < NB; i += 256) {
        int c = h[i];
        if (c) atomicAdd(&bcount[i], c);
    }
}

__global__ void k_bscan(const int* __restrict__ bcount, int* __restrict__ bstart,
                        int* __restrict__ gcur, int* __restrict__ rowptr,
                        int NB, int N, int E) {
    __shared__ int s[512];
    int t = threadIdx.x;
    int v = (t < NB) ? bcount[t] : 0;
    s[t] = v;
    __syncthreads();
    for (int off = 1; off < 512; off <<= 1) {
        int a = (t >= off) ? s[t - off] : 0;
        __syncthreads();
        s[t] += a;
        __syncthreads();
    }
    int excl = s[t] - v;
    if (t < NB) {
        bstart[t] = excl;
        gcur[t] = excl;
    }
    if (t == 0) {
        bstart[NB] = E;
        rowptr[N] = E;
    }
}

// pass A: scatter packed edges grouped by bucket per block.
// pack: dstlocal(8) << 20 | rel(3) << 17 | src(17)
__global__ void k_bscatter(const int* __restrict__ src, const int* __restrict__ dst,
                           const int* __restrict__ et, int* __restrict__ gcur,
                           unsigned* __restrict__ ebuf, int E, int NB) {
    __shared__ int h[512];
    __shared__ int basearr[512];
    int t = threadIdx.x;
    for (int i = t; i < NB; i += 256) h[i] = 0;
    __syncthreads();
    int e0 = blockIdx.x * CSR_CHUNK;
    int e1 = min(e0 + CSR_CHUNK, E);
    for (int i = e0 + t; i < e1; i += 256) atomicAdd(&h[dst[i] >> 8], 1);
    __syncthreads();
    for (int i = t; i < NB; i += 256) {
        int c = h[i];
        basearr[i] = c ? atomicAdd(&gcur[i], c) : 0;
        h[i] = 0;
    }
    __syncthreads();
    for (int i = e0 + t; i < e1; i += 256) {
        int d = dst[i];
        int b = d >> 8;
        int off = atomicAdd(&h[b], 1);
        ebuf[basearr[b] + off] =
            ((unsigned)(d & 255) << 20) | ((unsigned)et[i] << 17) | (unsigned)src[i];
    }
}

// pass B: one block per bucket. Per-node counts -> rowptr; scatter csr entries
// (rel<<17|src) into the bucket's contiguous window.
__global__ void k_bsort(const unsigned* __restrict__ ebuf, const int* __restrict__ bstart,
                        int* __restrict__ rowptr, int* __restrict__ csr, int N) {
    __shared__ int lh[256];
    __shared__ int ls[256];
    __shared__ int ss[256];
    int b = blockIdx.x, t = threadIdx.x;
    int e0 = bstart[b], e1 = bstart[b + 1];
    lh[t] = 0;
    __syncthreads();
    for (int i = e0 + t; i < e1; i += 256) atomicAdd(&lh[(ebuf[i] >> 20) & 255], 1);
    __syncthreads();
    int v = lh[t];
    ss[t] = v;
    __syncthreads();
    for (int off = 1; off < 256; off <<= 1) {
        int a = (t >= off) ? ss[t - off] : 0;
        __syncthreads();
        ss[t] += a;
        __syncthreads();
    }
    ls[t] = ss[t] - v;  // exclusive scan
    int node = b * 256 + t;
    if (node < N) rowptr[node] = e0 + ls[t];
    lh[t] = 0;
    __syncthreads();
    for (int i = e0 + t; i < e1; i += 256) {
        unsigned u = ebuf[i];
        int d = (u >> 20) & 255;
        int off = atomicAdd(&lh[d], 1);
        csr[e0 + ls[d] + off] = (int)(u & 0xFFFFF);
    }
}

// ---------------- weight prep ----------------

// Split-transpose into GEMM-B layout with K = i*8 + r (matches z layout):
// wt[o][i*8+r] = bf16(W[r][i][o]); lo = bf16 residual. K=512 rows total.
__global__ void k_wt2(const float* __restrict__ W, __hip_bfloat16* __restrict__ hi,
                      __hip_bfloat16* __restrict__ lo, int OUT, int total) {
    int t = blockIdx.x * blockDim.x + threadIdx.x;
    if (t < total) {
        int per = 64 * OUT;
        int r = t / per;
        int rem = t % per;
        int i = rem / OUT;
        int o = rem % OUT;
        float v = W[t];
        __hip_bfloat16 h = __float2bfloat16(v);
        __hip_bfloat16 l = __float2bfloat16(v - __bfloat162float(h));
        size_t idx = (size_t)o * 512 + i * 8 + r;
        hi[idx] = h;
        lo[idx] = l;
    }
}

// wq[r*64+i] = sum_o W[r,i,o]*Qv[o]; wk likewise. (fp32, tiny)
__global__ void k_wqk(const float* W, const float* Qv, const float* Kv,
                      float* wq, float* wk, int OUT) {
    int t = blockIdx.x * blockDim.x + threadIdx.x;
    if (t < 8 * 64) {
        int r = t >> 6, i = t & 63;
        const float* wrow = W + ((size_t)r * 64 + i) * OUT;
        float a = 0.f, b = 0.f;
        for (int o = 0; o < OUT; o++) {
            float w = wrow[o];
            a += w * Qv[o];
            b += w * Kv[o];
        }
        wq[t] = a;
        wk[t] = b;
    }
}

// ---------------- q/k projection + bf16 table emit ----------------
// Stages 64 node-rows via coalesced float4 into LDS, computes
// qn[n*8+r] = x[n,:].wq[r,:] (and kn), and emits the bf16 gather table.
__global__ __launch_bounds__(256) void k_qk2(
        const float* __restrict__ xin, const float* __restrict__ wq,
        const float* __restrict__ wk, float* __restrict__ qn,
        float* __restrict__ kn, unsigned short* __restrict__ xbb, int N) {
    __shared__ float xt[64][65];
    __shared__ float swq[8 * 65], swk[8 * 65];
    int t = threadIdx.x;
    int nb0 = blockIdx.x * 64;
    for (int i = t; i < 512; i += 256) {
        int r = i >> 6, c = i & 63;
        swq[r * 65 + c] = wq[i];
        swk[r * 65 + c] = wk[i];
    }
    for (int i = t; i < 1024; i += 256) {
        int ns = i >> 4;   // 16 float4 per row
        int c4 = i & 15;
        int n = nb0 + ns;
        float4 v = {0.f, 0.f, 0.f, 0.f};
        if (n < N) v = ((const float4*)xin)[(size_t)n * 16 + c4];
        xt[ns][c4 * 4 + 0] = v.x;
        xt[ns][c4 * 4 + 1] = v.y;
        xt[ns][c4 * 4 + 2] = v.z;
        xt[ns][c4 * 4 + 3] = v.w;
        if (n < N) {
            __hip_bfloat16 b0 = __float2bfloat16(v.x);
            __hip_bfloat16 b1 = __float2bfloat16(v.y);
            __hip_bfloat16 b2 = __float2bfloat16(v.z);
            __hip_bfloat16 b3 = __float2bfloat16(v.w);
            ushort4 o;
            o.x = *(unsigned short*)&b0;
            o.y = *(unsigned short*)&b1;
            o.z = *(unsigned short*)&b2;
            o.w = *(unsigned short*)&b3;
            *(ushort4*)(xbb + (size_t)n * 64 + c4 * 4) = o;
        }
    }
    __syncthreads();
#pragma unroll
    for (int g = t; g < 512; g += 256) {
        int ns = g >> 3, r = g & 7;
        int n = nb0 + ns;
        if (n < N) {
            float qa = 0.f, ka = 0.f;
#pragma unroll
            for (int i = 0; i < 64; i++) {
                float xv = xt[ns][i];
                qa += xv * swq[r * 65 + i];
                ka += xv * swk[r * 65 + i];
            }
            qn[(size_t)n * 8 + r] = qa;
            kn[(size_t)n * 8 + r] = ka;
        }
    }
}

// ---------------- aggregation into per-relation z (bf16) ----------------
// One wave per dst node. Single-pass softmax (no max-sub; logits O(+-6)).
// R11: relation-indexed accumulate moved to the LDS pipe. R10 post-mortem:
// VALUBusy 70% at 89 us = ~48 wave-VALU/edge — the 8-way switch was
// if-converted to ~8x(cmp+cndmask+fmac) per edge. Replacement: wave-private
// LDS accumulator [8 rel][64 ch], one ds_add_f32 per edge (DS pipe runs
// parallel to VALU — m114). LDS ops are in-order per wave, so the final
// per-rel reads need no barrier. Per-edge VALU drops to ~6
// (2 readlane + scalar-offset v_add + cvt + mul + load-issue).
// Tail slots carry pk=0,tv=0 -> harmless row-0 load + add of zero.
// HAZARD (R3/R4): all cross-lane ops run with the FULL wave active.
__global__ __launch_bounds__(256) void k_agg3(
        const int* __restrict__ rowptr, const int* __restrict__ csr,
        const float* __restrict__ qn, const float* __restrict__ kn,
        const unsigned short* __restrict__ xb,
        __hip_bfloat16* __restrict__ z, int N) {
    __shared__ float sacc[4 * 8 * 64];  // [wave][rel][chan], wave-private
    int wv = threadIdx.x >> 6;
    int lane = threadIdx.x & 63;
    int wid = (blockIdx.x * blockDim.x + threadIdx.x) >> 6;
    if (wid >= N) return;  // whole wave exits together
    float* myacc = &sacc[wv * 512];
#pragma unroll
    for (int r = 0; r < 8; r++) myacc[r * 64 + lane] = 0.f;
    // no barrier: region is wave-private and LDS is in-order per wave

    int r0 = rowptr[wid], r1 = rowptr[wid + 1];
    float qv = (lane < 8) ? qn[wid * 8 + lane] : 0.f;
    float denom = 0.f;

    for (int base = r0; base < r1; base += 64) {
        int s = base + lane;
        int pk = (s < r1) ? csr[s] : 0;
        int src = pk & 0x1FFFF;
        int rel = pk >> 17;
        float q = __shfl(qv, rel, 64);  // full wave active here
        float tv = 0.f;
        if (s < r1) {
            float v = q + kn[src * 8 + rel];
            v = (v >= 0.f) ? v : 0.2f * v;
            tv = __expf(v);
        }
        float ts = tv;
#pragma unroll
        for (int off = 32; off > 0; off >>= 1) ts += __shfl_xor(ts, off, 64);
        denom += ts;

        int cnt = min(64, r1 - base);
        int tvi = (int)__float_as_uint(tv);
        for (int j = 0; j < cnt; j += 16) {
            // broadcast 16 edges' metadata to SGPRs
            unsigned p[16];
            float t[16];
#pragma unroll
            for (int u = 0; u < 16; u++) {
                p[u] = (unsigned)__builtin_amdgcn_readlane(pk, j + u);
                t[u] = __uint_as_float((unsigned)__builtin_amdgcn_readlane(tvi, j + u));
            }
            // 16 independent gathers, issued back-to-back
            unsigned xu[16];
#pragma unroll
            for (int u = 0; u < 16; u++)
                xu[u] = (unsigned)xb[(size_t)(p[u] & 0x1FFFF) * 64 + lane];
            // accumulate on the LDS pipe: one ds_add_f32 per edge
#pragma unroll
            for (int u = 0; u < 16; u++) {
                float xv = __uint_as_float(xu[u] << 16);
                atomicAdd(&myacc[(int)((p[u] >> 17) << 6) + lane], t[u] * xv);
            }
        }
    }

    float inv = 1.f / (denom + 1e-16f);
    unsigned short u[8];
#pragma unroll
    for (int r = 0; r < 8; r++) {
        __hip_bfloat16 b = __float2bfloat16(myacc[r * 64 + lane] * inv);
        u[r] = *(unsigned short*)&b;
    }
    uint4 pack;
    pack.x = (unsigned)u[0] | ((unsigned)u[1] << 16);
    pack.y = (unsigned)u[2] | ((unsigned)u[3] << 16);
    pack.z = (unsigned)u[4] | ((unsigned)u[5] << 16);
    pack.w = (unsigned)u[6] | ((unsigned)u[7] << 16);
    *(uint4*)((unsigned short*)z + (size_t)wid * 512 + lane * 8) = pack;
}

// ---------------- final transform: out = z . Wcat (+bias, relu) ----------------
// GEMM M=N, K=512, N=OUT via mfma_f32_16x16x32_bf16.
template <int OUT, bool RELU>
__global__ __launch_bounds__(256) void k_zw(
        const __hip_bfloat16* __restrict__ z,
        const __hip_bfloat16* __restrict__ wthi, const __hip_bfloat16* __restrict__ wtlo,
        const float* __restrict__ bias, float* __restrict__ xout, int N) {
    using v8s = __attribute__((ext_vector_type(8))) short;
    using v4f = __attribute__((ext_vector_type(4))) float;
    constexpr int NT = OUT / 16;
    int wave = threadIdx.x >> 6;
    int lane = threadIdx.x & 63;
    int quad = lane >> 4;
    int l15 = lane & 15;
    int m0 = (blockIdx.x * 4 + wave) * 32;
    if (m0 >= N) return;

    v4f acc[NT][2];
#pragma unroll
    for (int nt = 0; nt < NT; nt++) {
        acc[nt][0] = (v4f){0.f, 0.f, 0.f, 0.f};
        acc[nt][1] = (v4f){0.f, 0.f, 0.f, 0.f};
    }

    const short* zp = (const short*)z;
    const short* wh = (const short*)wthi;
    const short* wl = (const short*)wtlo;
    int n0 = m0 + l15, n1 = m0 + 16 + l15;

    for (int k0 = 0; k0 < 512; k0 += 32) {
        int koff = k0 + quad * 8;
        v8s A0 = {}, A1 = {};
        if (n0 < N) A0 = *(const v8s*)(zp + (size_t)n0 * 512 + koff);
        if (n1 < N) A1 = *(const v8s*)(zp + (size_t)n1 * 512 + koff);
#pragma unroll
        for (int nt = 0; nt < NT; nt++) {
            v8s bh = *(const v8s*)(wh + (size_t)(nt * 16 + l15) * 512 + koff);
            v8s bl = *(const v8s*)(wl + (size_t)(nt * 16 + l15) * 512 + koff);
            acc[nt][0] = __builtin_amdgcn_mfma_f32_16x16x32_bf16(A0, bh, acc[nt][0], 0, 0, 0);
            acc[nt][0] = __builtin_amdgcn_mfma_f32_16x16x32_bf16(A0, bl, acc[nt][0], 0, 0, 0);
            acc[nt][1] = __builtin_amdgcn_mfma_f32_16x16x32_bf16(A1, bh, acc[nt][1], 0, 0, 0);
            acc[nt][1] = __builtin_amdgcn_mfma_f32_16x16x32_bf16(A1, bl, acc[nt][1], 0, 0, 0);
        }
    }

#pragma unroll
    for (int nt = 0; nt < NT; nt++) {
        float bcol = bias[nt * 16 + l15];
#pragma unroll
        for (int mm = 0; mm < 2; mm++) {
#pragma unroll
            for (int g = 0; g < 4; g++) {
                int row = m0 + mm * 16 + quad * 4 + g;
                if (row < N) {
                    float o = acc[nt][mm][g] + bcol;
                    if (RELU) o = fmaxf(o, 0.f);
                    xout[(size_t)row * OUT + nt * 16 + l15] = o;
                }
            }
        }
    }
}

// ---------------- host launch ----------------

extern "C" void kernel_launch(void* const* d_in, const int* in_sizes, int n_in,
                              void* d_out, int out_size, void* d_ws, size_t ws_size,
                              hipStream_t stream) {
    const float* x   = (const float*)d_in[0];
    const int*   ei  = (const int*)d_in[1];
    const int*   et  = (const int*)d_in[2];
    const float* W0  = (const float*)d_in[3];
    const float* Q0  = (const float*)d_in[4];
    const float* K0  = (const float*)d_in[5];
    const float* b0  = (const float*)d_in[6];
    const float* W1  = (const float*)d_in[7];
    const float* Q1  = (const float*)d_in[8];
    const float* K1  = (const float*)d_in[9];
    const float* b1  = (const float*)d_in[10];
    float* out = (float*)d_out;

    const int N = in_sizes[0] / 64;
    const int E = in_sizes[2];
    const int* src = ei;
    const int* dst = ei + E;
    const int NB = (N + 255) >> 8;  // <= 512

    char* p = (char*)d_ws;
    auto alloc = [&](size_t bytes) -> void* {
        void* r = (void*)p;
        p += ((bytes + 255) / 256) * 256;
        return r;
    };
    int* rowptr   = (int*)alloc((size_t)(N + 1) * 4);
    int* bcount   = (int*)alloc(513 * 4);
    int* bstart   = (int*)alloc(513 * 4);
    int* gcur     = (int*)alloc(513 * 4);
    unsigned* ebuf = (unsigned*)alloc((size_t)E * 4);
    int* csr      = (int*)alloc((size_t)E * 4);
    float* wq     = (float*)alloc(8 * 64 * 4);
    float* wk     = (float*)alloc(8 * 64 * 4);
    float* qn     = (float*)alloc((size_t)N * 8 * 4);
    float* kn     = (float*)alloc((size_t)N * 8 * 4);
    __hip_bfloat16* wthi = (__hip_bfloat16*)alloc((size_t)64 * 512 * 2);
    __hip_bfloat16* wtlo = (__hip_bfloat16*)alloc((size_t)64 * 512 * 2);
    __hip_bfloat16* z    = (__hip_bfloat16*)alloc((size_t)N * 512 * 2);
    float* h      = (float*)alloc((size_t)N * 64 * 4);
    unsigned short* xbb = (unsigned short*)alloc((size_t)N * 64 * 2);  // bf16 gather table

    // --- CSR build (bucketed counting sort; shared by both layers) ---
    int nchunks = (E + CSR_CHUNK - 1) / CSR_CHUNK;
    hipMemsetAsync(bcount, 0, (size_t)NB * 4, stream);
    k_bhist<<<nchunks, 256, 0, stream>>>(dst, bcount, E, NB);
    k_bscan<<<1, 512, 0, stream>>>(bcount, bstart, gcur, rowptr, NB, N, E);
    k_bscatter<<<nchunks, 256, 0, stream>>>(src, dst, et, gcur, ebuf, E, NB);
    k_bsort<<<NB, 256, 0, stream>>>(ebuf, bstart, rowptr, csr, N);

    int naggb = (N * 64 + 255) / 256;
    int nzwb = (N + 127) / 128;
    int nqkb = (N + 63) / 64;

    // --- layer 0: 64 -> 64, relu ---
    k_wqk<<<2, 256, 0, stream>>>(W0, Q0, K0, wq, wk, 64);
    k_qk2<<<nqkb, 256, 0, stream>>>(x, wq, wk, qn, kn, xbb, N);
    k_wt2<<<(8 * 64 * 64 + 255) / 256, 256, 0, stream>>>(W0, wthi, wtlo, 64, 8 * 64 * 64);
    k_agg3<<<naggb, 256, 0, stream>>>(rowptr, csr, qn, kn, xbb, z, N);
    k_zw<64, true><<<nzwb, 256, 0, stream>>>(z, wthi, wtlo, b0, h, N);

    // --- layer 1: 64 -> 32, no relu ---
    k_wqk<<<2, 256, 0, stream>>>(W1, Q1, K1, wq, wk, 32);
    k_qk2<<<nqkb, 256, 0, stream>>>(h, wq, wk, qn, kn, xbb, N);
    k_wt2<<<(8 * 64 * 32 + 255) / 256, 256, 0, stream>>>(W1, wthi, wtlo, 32, 8 * 64 * 32);
    k_agg3<<<naggb, 256, 0, stream>>>(rowptr, csr, qn, kn, xbb, z, N);
    k_zw<32, false><<<nzwb, 256, 0, stream>>>(z, wthi, wtlo, b1, out, N);
}

// Round 12
// 490.045 us; speedup vs baseline: 3.8224x; 3.8224x over previous
//
#include <hip/hip_runtime.h>
#include <hip/hip_bf16.h>
#include <math.h>

// ---------------- bucketed CSR build ----------------
// bucket = dst >> 8 (256 nodes/bucket). NB = ceil(N/256) <= 512.
// R6: single-pass random 4B scatter caused 16x write amplification -> two-level
// counting sort. R10's smaller chunks REGRESSED (LDS init/flush overhead):
// 8192-edge chunks retained. R12: pass B sorts by 11-bit key
// (dstlocal*8 + rel) so each node's row is RELATION-SORTED -> k_agg4 can use
// run-length flushes instead of a per-edge 8-way select (which was ~48
// VALU/edge in R10, and LDS atomics were 8.7x worse in R11).

#define CSR_CHUNK 8192

__global__ void k_bhist(const int* __restrict__ dst, int* __restrict__ bcount,
                        int E, int NB) {
    __shared__ int h[512];
    int t = threadIdx.x;
    for (int i = t; i < NB; i += 256) h[i] = 0;
    __syncthreads();
    int e0 = blockIdx.x * CSR_CHUNK;
    int e1 = min(e0 + CSR_CHUNK, E);
    for (int i = e0 + t; i < e1; i += 256) atomicAdd(&h[dst[i] >> 8], 1);
    __syncthreads();
    for (int i = t; i < NB; i += 256) {
        int c = h[i];
        if (c) atomicAdd(&bcount[i], c);
    }
}

__global__ void k_bscan(const int* __restrict__ bcount, int* __restrict__ bstart,
                        int* __restrict__ gcur, int* __restrict__ rowptr,
                        int NB, int N, int E) {
    __shared__ int s[512];
    int t = threadIdx.x;
    int v = (t < NB) ? bcount[t] : 0;
    s[t] = v;
    __syncthreads();
    for (int off = 1; off < 512; off <<= 1) {
        int a = (t >= off) ? s[t - off] : 0;
        __syncthreads();
        s[t] += a;
        __syncthreads();
    }
    int excl = s[t] - v;
    if (t < NB) {
        bstart[t] = excl;
        gcur[t] = excl;
    }
    if (t == 0) {
        bstart[NB] = E;
        rowptr[N] = E;
    }
}

// pass A: scatter packed edges grouped by bucket per block.
// pack: dstlocal(8) << 20 | rel(3) << 17 | src(17)
__global__ void k_bscatter(const int* __restrict__ src, const int* __restrict__ dst,
                           const int* __restrict__ et, int* __restrict__ gcur,
                           unsigned* __restrict__ ebuf, int E, int NB) {
    __shared__ int h[512];
    __shared__ int basearr[512];
    int t = threadIdx.x;
    for (int i = t; i < NB; i += 256) h[i] = 0;
    __syncthreads();
    int e0 = blockIdx.x * CSR_CHUNK;
    int e1 = min(e0 + CSR_CHUNK, E);
    for (int i = e0 + t; i < e1; i += 256) atomicAdd(&h[dst[i] >> 8], 1);
    __syncthreads();
    for (int i = t; i < NB; i += 256) {
        int c = h[i];
        basearr[i] = c ? atomicAdd(&gcur[i], c) : 0;
        h[i] = 0;
    }
    __syncthreads();
    for (int i = e0 + t; i < e1; i += 256) {
        int d = dst[i];
        int b = d >> 8;
        int off = atomicAdd(&h[b], 1);
        ebuf[basearr[b] + off] =
            ((unsigned)(d & 255) << 20) | ((unsigned)et[i] << 17) | (unsigned)src[i];
    }
}

// pass B: one block per bucket. 2048-bin (node,rel) counting sort -> rowptr
// (per node) + csr entries (rel<<17|src) sorted by (node, rel).
__global__ void k_bsort(const unsigned* __restrict__ ebuf, const int* __restrict__ bstart,
                        int* __restrict__ rowptr, int* __restrict__ csr, int N) {
    __shared__ int lh[2048];
    __shared__ int ls[2048];
    __shared__ int ss[256];
    int b = blockIdx.x, t = threadIdx.x;
    int e0 = bstart[b], e1 = bstart[b + 1];
    for (int i = t; i < 2048; i += 256) lh[i] = 0;
    __syncthreads();
    for (int i = e0 + t; i < e1; i += 256) {
        unsigned u = ebuf[i];
        atomicAdd(&lh[(int)(((u >> 20) & 255) * 8 + ((u >> 17) & 7))], 1);
    }
    __syncthreads();
    // each thread scans its 8 consecutive bins (bins of node t)
    int loc[8];
    int s = 0;
#pragma unroll
    for (int j = 0; j < 8; j++) {
        loc[j] = s;
        s += lh[t * 8 + j];
    }
    ss[t] = s;
    __syncthreads();
    for (int off = 1; off < 256; off <<= 1) {
        int a = (t >= off) ? ss[t - off] : 0;
        __syncthreads();
        ss[t] += a;
        __syncthreads();
    }
    int excl = ss[t] - s;
#pragma unroll
    for (int j = 0; j < 8; j++) ls[t * 8 + j] = excl + loc[j];
    int node = b * 256 + t;
    if (node < N) rowptr[node] = e0 + excl;
    __syncthreads();
    for (int i = t; i < 2048; i += 256) lh[i] = 0;
    __syncthreads();
    for (int i = e0 + t; i < e1; i += 256) {
        unsigned u = ebuf[i];
        int key = (int)(((u >> 20) & 255) * 8 + ((u >> 17) & 7));
        int off = atomicAdd(&lh[key], 1);
        csr[e0 + ls[key] + off] = (int)(u & 0xFFFFF);
    }
}

// ---------------- weight prep ----------------

// Split-transpose into GEMM-B layout with K = i*8 + r (matches z layout):
// wt[o][i*8+r] = bf16(W[r][i][o]); lo = bf16 residual. K=512 rows total.
__global__ void k_wt2(const float* __restrict__ W, __hip_bfloat16* __restrict__ hi,
                      __hip_bfloat16* __restrict__ lo, int OUT, int total) {
    int t = blockIdx.x * blockDim.x + threadIdx.x;
    if (t < total) {
        int per = 64 * OUT;
        int r = t / per;
        int rem = t % per;
        int i = rem / OUT;
        int o = rem % OUT;
        float v = W[t];
        __hip_bfloat16 h = __float2bfloat16(v);
        __hip_bfloat16 l = __float2bfloat16(v - __bfloat162float(h));
        size_t idx = (size_t)o * 512 + i * 8 + r;
        hi[idx] = h;
        lo[idx] = l;
    }
}

// wq[r*64+i] = sum_o W[r,i,o]*Qv[o]; wk likewise. (fp32, tiny)
__global__ void k_wqk(const float* W, const float* Qv, const float* Kv,
                      float* wq, float* wk, int OUT) {
    int t = blockIdx.x * blockDim.x + threadIdx.x;
    if (t < 8 * 64) {
        int r = t >> 6, i = t & 63;
        const float* wrow = W + ((size_t)r * 64 + i) * OUT;
        float a = 0.f, b = 0.f;
        for (int o = 0; o < OUT; o++) {
            float w = wrow[o];
            a += w * Qv[o];
            b += w * Kv[o];
        }
        wq[t] = a;
        wk[t] = b;
    }
}

// ---------------- q/k projection + bf16 table emit ----------------
__global__ __launch_bounds__(256) void k_qk2(
        const float* __restrict__ xin, const float* __restrict__ wq,
        const float* __restrict__ wk, float* __restrict__ qn,
        float* __restrict__ kn, unsigned short* __restrict__ xbb, int N) {
    __shared__ float xt[64][65];
    __shared__ float swq[8 * 65], swk[8 * 65];
    int t = threadIdx.x;
    int nb0 = blockIdx.x * 64;
    for (int i = t; i < 512; i += 256) {
        int r = i >> 6, c = i & 63;
        swq[r * 65 + c] = wq[i];
        swk[r * 65 + c] = wk[i];
    }
    for (int i = t; i < 1024; i += 256) {
        int ns = i >> 4;   // 16 float4 per row
        int c4 = i & 15;
        int n = nb0 + ns;
        float4 v = {0.f, 0.f, 0.f, 0.f};
        if (n < N) v = ((const float4*)xin)[(size_t)n * 16 + c4];
        xt[ns][c4 * 4 + 0] = v.x;
        xt[ns][c4 * 4 + 1] = v.y;
        xt[ns][c4 * 4 + 2] = v.z;
        xt[ns][c4 * 4 + 3] = v.w;
        if (n < N) {
            __hip_bfloat16 b0 = __float2bfloat16(v.x);
            __hip_bfloat16 b1 = __float2bfloat16(v.y);
            __hip_bfloat16 b2 = __float2bfloat16(v.z);
            __hip_bfloat16 b3 = __float2bfloat16(v.w);
            ushort4 o;
            o.x = *(unsigned short*)&b0;
            o.y = *(unsigned short*)&b1;
            o.z = *(unsigned short*)&b2;
            o.w = *(unsigned short*)&b3;
            *(ushort4*)(xbb + (size_t)n * 64 + c4 * 4) = o;
        }
    }
    __syncthreads();
#pragma unroll
    for (int g = t; g < 512; g += 256) {
        int ns = g >> 3, r = g & 7;
        int n = nb0 + ns;
        if (n < N) {
            float qa = 0.f, ka = 0.f;
#pragma unroll
            for (int i = 0; i < 64; i++) {
                float xv = xt[ns][i];
                qa += xv * swq[r * 65 + i];
                ka += xv * swk[r * 65 + i];
            }
            qn[(size_t)n * 8 + r] = qa;
            kn[(size_t)n * 8 + r] = ka;
        }
    }
}

// ---------------- aggregation into per-relation z (bf16) ----------------
// One wave per dst node. Single-pass softmax (no max-sub; logits O(+-6)).
// R12: CSR rows are rel-sorted -> run-length accumulation. Per edge:
// racc += t*xv (VALU ~8/edge); the 8-way flush switch runs only at run
// boundaries (<=8 per node), guarded by a UNIFORM scalar compare
// (s_cmp+s_cbranch on SALU). R10's per-edge switch was ~48 VALU/edge;
// R11's per-edge LDS atomic was 8.7x worse (ds_add_f32 throughput).
// Tail slots carry pk=0,tv=0 -> harmless flush-to-rel0 + add of zero.
// HAZARD (R3/R4): all cross-lane ops run with the FULL wave active.
__global__ __launch_bounds__(256) void k_agg4(
        const int* __restrict__ rowptr, const int* __restrict__ csr,
        const float* __restrict__ qn, const float* __restrict__ kn,
        const unsigned short* __restrict__ xb,
        __hip_bfloat16* __restrict__ z, int N) {
    int wid = (blockIdx.x * blockDim.x + threadIdx.x) >> 6;
    int lane = threadIdx.x & 63;
    if (wid >= N) return;
    int r0 = rowptr[wid], r1 = rowptr[wid + 1];

    float qv = (lane < 8) ? qn[wid * 8 + lane] : 0.f;

    float denom = 0.f;
    float a0 = 0.f, a1 = 0.f, a2 = 0.f, a3 = 0.f;
    float a4 = 0.f, a5 = 0.f, a6 = 0.f, a7 = 0.f;
    int currel = 0;      // SGPR (uniform)
    float racc = 0.f;    // current run's accumulator

    for (int base = r0; base < r1; base += 64) {
        int s = base + lane;
        int pk = (s < r1) ? csr[s] : 0;
        int src = pk & 0x1FFFF;
        int rel = pk >> 17;
        float q = __shfl(qv, rel, 64);  // full wave active here
        float tv = 0.f;
        if (s < r1) {
            float v = q + kn[src * 8 + rel];
            v = (v >= 0.f) ? v : 0.2f * v;
            tv = __expf(v);
        }
        float ts = tv;
#pragma unroll
        for (int off = 32; off > 0; off >>= 1) ts += __shfl_xor(ts, off, 64);
        denom += ts;

        int cnt = min(64, r1 - base);
        int tvi = (int)__float_as_uint(tv);
        for (int j = 0; j < cnt; j += 16) {
            // broadcast 16 edges' metadata to SGPRs
            unsigned p[16];
            float t[16];
#pragma unroll
            for (int u = 0; u < 16; u++) {
                p[u] = (unsigned)__builtin_amdgcn_readlane(pk, j + u);
                t[u] = __uint_as_float((unsigned)__builtin_amdgcn_readlane(tvi, j + u));
            }
            // 16 independent gathers, issued back-to-back
            unsigned xu[16];
#pragma unroll
            for (int u = 0; u < 16; u++)
                xu[u] = (unsigned)xb[(size_t)(p[u] & 0x1FFFF) * 64 + lane];
            // run-length accumulate: flush only when (uniform) rel changes
#pragma unroll
            for (int u = 0; u < 16; u++) {
                int rl = (int)(p[u] >> 17);  // SGPR
                if (rl != currel) {          // uniform scalar branch
                    switch (currel) {
                        case 0: a0 += racc; break;
                        case 1: a1 += racc; break;
                        case 2: a2 += racc; break;
                        case 3: a3 += racc; break;
                        case 4: a4 += racc; break;
                        case 5: a5 += racc; break;
                        case 6: a6 += racc; break;
                        case 7: a7 += racc; break;
                    }
                    currel = rl;
                    racc = 0.f;
                }
                racc += t[u] * __uint_as_float(xu[u] << 16);
            }
        }
    }
    // final flush
    switch (currel) {
        case 0: a0 += racc; break;
        case 1: a1 += racc; break;
        case 2: a2 += racc; break;
        case 3: a3 += racc; break;
        case 4: a4 += racc; break;
        case 5: a5 += racc; break;
        case 6: a6 += racc; break;
        case 7: a7 += racc; break;
    }

    float inv = 1.f / (denom + 1e-16f);
    unsigned short u[8];
    float av[8] = {a0, a1, a2, a3, a4, a5, a6, a7};
#pragma unroll
    for (int r = 0; r < 8; r++) {
        __hip_bfloat16 b = __float2bfloat16(av[r] * inv);
        u[r] = *(unsigned short*)&b;
    }
    uint4 pack;
    pack.x = (unsigned)u[0] | ((unsigned)u[1] << 16);
    pack.y = (unsigned)u[2] | ((unsigned)u[3] << 16);
    pack.z = (unsigned)u[4] | ((unsigned)u[5] << 16);
    pack.w = (unsigned)u[6] | ((unsigned)u[7] << 16);
    *(uint4*)((unsigned short*)z + (size_t)wid * 512 + lane * 8) = pack;
}

// ---------------- final transform: out = z . Wcat (+bias, relu) ----------------
// GEMM M=N, K=512, N=OUT via mfma_f32_16x16x32_bf16.
template <int OUT, bool RELU>
__global__ __launch_bounds__(256) void k_zw(
        const __hip_bfloat16* __restrict__ z,
        const __hip_bfloat16* __restrict__ wthi, const __hip_bfloat16* __restrict__ wtlo,
        const float* __restrict__ bias, float* __restrict__ xout, int N) {
    using v8s = __attribute__((ext_vector_type(8))) short;
    using v4f = __attribute__((ext_vector_type(4))) float;
    constexpr int NT = OUT / 16;
    int wave = threadIdx.x >> 6;
    int lane = threadIdx.x & 63;
    int quad = lane >> 4;
    int l15 = lane & 15;
    int m0 = (blockIdx.x * 4 + wave) * 32;
    if (m0 >= N) return;

    v4f acc[NT][2];
#pragma unroll
    for (int nt = 0; nt < NT; nt++) {
        acc[nt][0] = (v4f){0.f, 0.f, 0.f, 0.f};
        acc[nt][1] = (v4f){0.f, 0.f, 0.f, 0.f};
    }

    const short* zp = (const short*)z;
    const short* wh = (const short*)wthi;
    const short* wl = (const short*)wtlo;
    int n0 = m0 + l15, n1 = m0 + 16 + l15;

    for (int k0 = 0; k0 < 512; k0 += 32) {
        int koff = k0 + quad * 8;
        v8s A0 = {}, A1 = {};
        if (n0 < N) A0 = *(const v8s*)(zp + (size_t)n0 * 512 + koff);
        if (n1 < N) A1 = *(const v8s*)(zp + (size_t)n1 * 512 + koff);
#pragma unroll
        for (int nt = 0; nt < NT; nt++) {
            v8s bh = *(const v8s*)(wh + (size_t)(nt * 16 + l15) * 512 + koff);
            v8s bl = *(const v8s*)(wl + (size_t)(nt * 16 + l15) * 512 + koff);
            acc[nt][0] = __builtin_amdgcn_mfma_f32_16x16x32_bf16(A0, bh, acc[nt][0], 0, 0, 0);
            acc[nt][0] = __builtin_amdgcn_mfma_f32_16x16x32_bf16(A0, bl, acc[nt][0], 0, 0, 0);
            acc[nt][1] = __builtin_amdgcn_mfma_f32_16x16x32_bf16(A1, bh, acc[nt][1], 0, 0, 0);
            acc[nt][1] = __builtin_amdgcn_mfma_f32_16x16x32_bf16(A1, bl, acc[nt][1], 0, 0, 0);
        }
    }

#pragma unroll
    for (int nt = 0; nt < NT; nt++) {
        float bcol = bias[nt * 16 + l15];
#pragma unroll
        for (int mm = 0; mm < 2; mm++) {
#pragma unroll
            for (int g = 0; g < 4; g++) {
                int row = m0 + mm * 16 + quad * 4 + g;
                if (row < N) {
                    float o = acc[nt][mm][g] + bcol;
                    if (RELU) o = fmaxf(o, 0.f);
                    xout[(size_t)row * OUT + nt * 16 + l15] = o;
                }
            }
        }
    }
}

// ---------------- host launch ----------------

extern "C" void kernel_launch(void* const* d_in, const int* in_sizes, int n_in,
                              void* d_out, int out_size, void* d_ws, size_t ws_size,
                              hipStream_t stream) {
    const float* x   = (const float*)d_in[0];
    const int*   ei  = (const int*)d_in[1];
    const int*   et  = (const int*)d_in[2];
    const float* W0  = (const float*)d_in[3];
    const float* Q0  = (const float*)d_in[4];
    const float* K0  = (const float*)d_in[5];
    const float* b0  = (const float*)d_in[6];
    const float* W1  = (const float*)d_in[7];
    const float* Q1  = (const float*)d_in[8];
    const float* K1  = (const float*)d_in[9];
    const float* b1  = (const float*)d_in[10];
    float* out = (float*)d_out;

    const int N = in_sizes[0] / 64;
    const int E = in_sizes[2];
    const int* src = ei;
    const int* dst = ei + E;
    const int NB = (N + 255) >> 8;  // <= 512

    char* p = (char*)d_ws;
    auto alloc = [&](size_t bytes) -> void* {
        void* r = (void*)p;
        p += ((bytes + 255) / 256) * 256;
        return r;
    };
    int* rowptr   = (int*)alloc((size_t)(N + 1) * 4);
    int* bcount   = (int*)alloc(513 * 4);
    int* bstart   = (int*)alloc(513 * 4);
    int* gcur     = (int*)alloc(513 * 4);
    unsigned* ebuf = (unsigned*)alloc((size_t)E * 4);
    int* csr      = (int*)alloc((size_t)E * 4);
    float* wq     = (float*)alloc(8 * 64 * 4);
    float* wk     = (float*)alloc(8 * 64 * 4);
    float* qn     = (float*)alloc((size_t)N * 8 * 4);
    float* kn     = (float*)alloc((size_t)N * 8 * 4);
    __hip_bfloat16* wthi = (__hip_bfloat16*)alloc((size_t)64 * 512 * 2);
    __hip_bfloat16* wtlo = (__hip_bfloat16*)alloc((size_t)64 * 512 * 2);
    __hip_bfloat16* z    = (__hip_bfloat16*)alloc((size_t)N * 512 * 2);
    float* h      = (float*)alloc((size_t)N * 64 * 4);
    unsigned short* xbb = (unsigned short*)alloc((size_t)N * 64 * 2);  // bf16 gather table

    // --- CSR build (bucketed counting sort; shared by both layers) ---
    int nchunks = (E + CSR_CHUNK - 1) / CSR_CHUNK;
    hipMemsetAsync(bcount, 0, (size_t)NB * 4, stream);
    k_bhist<<<nchunks, 256, 0, stream>>>(dst, bcount, E, NB);
    k_bscan<<<1, 512, 0, stream>>>(bcount, bstart, gcur, rowptr, NB, N, E);
    k_bscatter<<<nchunks, 256, 0, stream>>>(src, dst, et, gcur, ebuf, E, NB);
    k_bsort<<<NB, 256, 0, stream>>>(ebuf, bstart, rowptr, csr, N);

    int naggb = (N * 64 + 255) / 256;
    int nzwb = (N + 127) / 128;
    int nqkb = (N + 63) / 64;

    // --- layer 0: 64 -> 64, relu ---
    k_wqk<<<2, 256, 0, stream>>>(W0, Q0, K0, wq, wk, 64);
    k_qk2<<<nqkb, 256, 0, stream>>>(x, wq, wk, qn, kn, xbb, N);
    k_wt2<<<(8 * 64 * 64 + 255) / 256, 256, 0, stream>>>(W0, wthi, wtlo, 64, 8 * 64 * 64);
    k_agg4<<<naggb, 256, 0, stream>>>(rowptr, csr, qn, kn, xbb, z, N);
    k_zw<64, true><<<nzwb, 256, 0, stream>>>(z, wthi, wtlo, b0, h, N);

    // --- layer 1: 64 -> 32, no relu ---
    k_wqk<<<2, 256, 0, stream>>>(W1, Q1, K1, wq, wk, 32);
    k_qk2<<<nqkb, 256, 0, stream>>>(h, wq, wk, qn, kn, xbb, N);
    k_wt2<<<(8 * 64 * 32 + 255) / 256, 256, 0, stream>>>(W1, wthi, wtlo, 32, 8 * 64 * 32);
    k_agg4<<<naggb, 256, 0, stream>>>(rowptr, csr, qn, kn, xbb, z, N);
    k_zw<32, false><<<nzwb, 256, 0, stream>>>(z, wthi, wtlo, b1, out, N);
}

// Round 13
// 446.094 us; speedup vs baseline: 4.1990x; 1.0985x over previous
//
#include <hip/hip_runtime.h>
#include <hip/hip_bf16.h>
#include <math.h>

// ---------------- bucketed CSR build ----------------
// bucket = dst >> 8 (256 nodes/bucket). NB = ceil(N/256) <= 512.
// R6: single-pass random 4B scatter caused 16x write amplification -> two-level
// counting sort. R10's smaller chunks REGRESSED (LDS init/flush overhead).
// R12: pass B sorts by 11-bit key (dstlocal*8 + rel) so each node's row is
// RELATION-SORTED -> run-length flushes in the agg loop (per-edge 8-way select
// was ~48 VALU/edge in R10; per-edge LDS atomics were 8.7x worse in R11).

#define CSR_CHUNK 8192

__global__ void k_bhist(const int* __restrict__ dst, int* __restrict__ bcount,
                        int E, int NB) {
    __shared__ int h[512];
    int t = threadIdx.x;
    for (int i = t; i < NB; i += 256) h[i] = 0;
    __syncthreads();
    int e0 = blockIdx.x * CSR_CHUNK;
    int e1 = min(e0 + CSR_CHUNK, E);
    for (int i = e0 + t; i < e1; i += 256) atomicAdd(&h[dst[i] >> 8], 1);
    __syncthreads();
    for (int i = t; i < NB; i += 256) {
        int c = h[i];
        if (c) atomicAdd(&bcount[i], c);
    }
}

__global__ void k_bscan(const int* __restrict__ bcount, int* __restrict__ bstart,
                        int* __restrict__ gcur, int* __restrict__ rowptr,
                        int NB, int N, int E) {
    __shared__ int s[512];
    int t = threadIdx.x;
    int v = (t < NB) ? bcount[t] : 0;
    s[t] = v;
    __syncthreads();
    for (int off = 1; off < 512; off <<= 1) {
        int a = (t >= off) ? s[t - off] : 0;
        __syncthreads();
        s[t] += a;
        __syncthreads();
    }
    int excl = s[t] - v;
    if (t < NB) {
        bstart[t] = excl;
        gcur[t] = excl;
    }
    if (t == 0) {
        bstart[NB] = E;
        rowptr[N] = E;
    }
}

// pass A: scatter packed edges grouped by bucket per block.
// pack: dstlocal(8) << 20 | rel(3) << 17 | src(17)
__global__ void k_bscatter(const int* __restrict__ src, const int* __restrict__ dst,
                           const int* __restrict__ et, int* __restrict__ gcur,
                           unsigned* __restrict__ ebuf, int E, int NB) {
    __shared__ int h[512];
    __shared__ int basearr[512];
    int t = threadIdx.x;
    for (int i = t; i < NB; i += 256) h[i] = 0;
    __syncthreads();
    int e0 = blockIdx.x * CSR_CHUNK;
    int e1 = min(e0 + CSR_CHUNK, E);
    for (int i = e0 + t; i < e1; i += 256) atomicAdd(&h[dst[i] >> 8], 1);
    __syncthreads();
    for (int i = t; i < NB; i += 256) {
        int c = h[i];
        basearr[i] = c ? atomicAdd(&gcur[i], c) : 0;
        h[i] = 0;
    }
    __syncthreads();
    for (int i = e0 + t; i < e1; i += 256) {
        int d = dst[i];
        int b = d >> 8;
        int off = atomicAdd(&h[b], 1);
        ebuf[basearr[b] + off] =
            ((unsigned)(d & 255) << 20) | ((unsigned)et[i] << 17) | (unsigned)src[i];
    }
}

// pass B: one block per bucket. 2048-bin (node,rel) counting sort -> rowptr
// (per node) + csr entries (rel<<17|src) sorted by (node, rel).
__global__ void k_bsort(const unsigned* __restrict__ ebuf, const int* __restrict__ bstart,
                        int* __restrict__ rowptr, int* __restrict__ csr, int N) {
    __shared__ int lh[2048];
    __shared__ int ls[2048];
    __shared__ int ss[256];
    int b = blockIdx.x, t = threadIdx.x;
    int e0 = bstart[b], e1 = bstart[b + 1];
    for (int i = t; i < 2048; i += 256) lh[i] = 0;
    __syncthreads();
    for (int i = e0 + t; i < e1; i += 256) {
        unsigned u = ebuf[i];
        atomicAdd(&lh[(int)(((u >> 20) & 255) * 8 + ((u >> 17) & 7))], 1);
    }
    __syncthreads();
    int loc[8];
    int s = 0;
#pragma unroll
    for (int j = 0; j < 8; j++) {
        loc[j] = s;
        s += lh[t * 8 + j];
    }
    ss[t] = s;
    __syncthreads();
    for (int off = 1; off < 256; off <<= 1) {
        int a = (t >= off) ? ss[t - off] : 0;
        __syncthreads();
        ss[t] += a;
        __syncthreads();
    }
    int excl = ss[t] - s;
#pragma unroll
    for (int j = 0; j < 8; j++) ls[t * 8 + j] = excl + loc[j];
    int node = b * 256 + t;
    if (node < N) rowptr[node] = e0 + excl;
    __syncthreads();
    for (int i = t; i < 2048; i += 256) lh[i] = 0;
    __syncthreads();
    for (int i = e0 + t; i < e1; i += 256) {
        unsigned u = ebuf[i];
        int key = (int)(((u >> 20) & 255) * 8 + ((u >> 17) & 7));
        int off = atomicAdd(&lh[key], 1);
        csr[e0 + ls[key] + off] = (int)(u & 0xFFFFF);
    }
}

// ---------------- weight prep ----------------

// Split-transpose into GEMM-B layout with K = i*8 + r (matches z layout):
// wt[o][i*8+r] = bf16(W[r][i][o]); lo = bf16 residual. K=512 rows total.
__global__ void k_wt2(const float* __restrict__ W, __hip_bfloat16* __restrict__ hi,
                      __hip_bfloat16* __restrict__ lo, int OUT, int total) {
    int t = blockIdx.x * blockDim.x + threadIdx.x;
    if (t < total) {
        int per = 64 * OUT;
        int r = t / per;
        int rem = t % per;
        int i = rem / OUT;
        int o = rem % OUT;
        float v = W[t];
        __hip_bfloat16 h = __float2bfloat16(v);
        __hip_bfloat16 l = __float2bfloat16(v - __bfloat162float(h));
        size_t idx = (size_t)o * 512 + i * 8 + r;
        hi[idx] = h;
        lo[idx] = l;
    }
}

// wq[r*64+i] = sum_o W[r,i,o]*Qv[o]; wk likewise. (fp32, tiny)
__global__ void k_wqk(const float* W, const float* Qv, const float* Kv,
                      float* wq, float* wk, int OUT) {
    int t = blockIdx.x * blockDim.x + threadIdx.x;
    if (t < 8 * 64) {
        int r = t >> 6, i = t & 63;
        const float* wrow = W + ((size_t)r * 64 + i) * OUT;
        float a = 0.f, b = 0.f;
        for (int o = 0; o < OUT; o++) {
            float w = wrow[o];
            a += w * Qv[o];
            b += w * Kv[o];
        }
        wq[t] = a;
        wk[t] = b;
    }
}

// ---------------- q/k projection + bf16 table emit ----------------
__global__ __launch_bounds__(256) void k_qk2(
        const float* __restrict__ xin, const float* __restrict__ wq,
        const float* __restrict__ wk, float* __restrict__ qn,
        float* __restrict__ kn, unsigned short* __restrict__ xbb, int N) {
    __shared__ float xt[64][65];
    __shared__ float swq[8 * 65], swk[8 * 65];
    int t = threadIdx.x;
    int nb0 = blockIdx.x * 64;
    for (int i = t; i < 512; i += 256) {
        int r = i >> 6, c = i & 63;
        swq[r * 65 + c] = wq[i];
        swk[r * 65 + c] = wk[i];
    }
    for (int i = t; i < 1024; i += 256) {
        int ns = i >> 4;   // 16 float4 per row
        int c4 = i & 15;
        int n = nb0 + ns;
        float4 v = {0.f, 0.f, 0.f, 0.f};
        if (n < N) v = ((const float4*)xin)[(size_t)n * 16 + c4];
        xt[ns][c4 * 4 + 0] = v.x;
        xt[ns][c4 * 4 + 1] = v.y;
        xt[ns][c4 * 4 + 2] = v.z;
        xt[ns][c4 * 4 + 3] = v.w;
        if (n < N) {
            __hip_bfloat16 b0 = __float2bfloat16(v.x);
            __hip_bfloat16 b1 = __float2bfloat16(v.y);
            __hip_bfloat16 b2 = __float2bfloat16(v.z);
            __hip_bfloat16 b3 = __float2bfloat16(v.w);
            ushort4 o;
            o.x = *(unsigned short*)&b0;
            o.y = *(unsigned short*)&b1;
            o.z = *(unsigned short*)&b2;
            o.w = *(unsigned short*)&b3;
            *(ushort4*)(xbb + (size_t)n * 64 + c4 * 4) = o;
        }
    }
    __syncthreads();
#pragma unroll
    for (int g = t; g < 512; g += 256) {
        int ns = g >> 3, r = g & 7;
        int n = nb0 + ns;
        if (n < N) {
            float qa = 0.f, ka = 0.f;
#pragma unroll
            for (int i = 0; i < 64; i++) {
                float xv = xt[ns][i];
                qa += xv * swq[r * 65 + i];
                ka += xv * swk[r * 65 + i];
            }
            qn[(size_t)n * 8 + r] = qa;
            kn[(size_t)n * 8 + r] = ka;
        }
    }
}

// ---------------- fused aggregation + transform (R13) ----------------
// R12 post-mortem: k_zw was latency-bound (82 us, MfmaUtil 6%, Occ 26%) on
// scattered A-reads of the 102 MB z table, and z cost a 100 MB write + 102 MB
// read purely to round-trip between kernels. Fusion: one block = 4 waves =
// 16 nodes. Phase 1 (per wave, 4 nodes): R12's run-length agg loop -> bf16
// z-row into a 16 x 520-padded LDS tile (pad -> A-frag ds_read_b128 lands
// 2 lanes/bank = free, m136). Phase 2: wave wv computes 16-col tile wv of
// out = z.Wcat (+bias, relu) with 32 MFMAs; B (W hi/lo) is L2-hot.
// wid<N guard is wave-uniform -> full exec at every cross-lane op (R3/R4).
// Tail zt rows zero-filled so MFMA never sees uninitialized LDS.
#define ZSTR 520
template <int OUT, bool RELU>
__global__ __launch_bounds__(256) void k_fused(
        const int* __restrict__ rowptr, const int* __restrict__ csr,
        const float* __restrict__ qn, const float* __restrict__ kn,
        const unsigned short* __restrict__ xb,
        const __hip_bfloat16* __restrict__ wthi,
        const __hip_bfloat16* __restrict__ wtlo,
        const float* __restrict__ bias, float* __restrict__ xout, int N) {
    using v8s = __attribute__((ext_vector_type(8))) short;
    using v4f = __attribute__((ext_vector_type(4))) float;
    __shared__ unsigned short zt[16 * ZSTR];
    int wv = threadIdx.x >> 6;
    int lane = threadIdx.x & 63;
    int nb0 = blockIdx.x * 16;

    // ---- phase 1: aggregate 4 nodes per wave into LDS z-tile ----
    for (int q = 0; q < 4; q++) {
        int nl = wv * 4 + q;       // local row 0..15
        int wid = nb0 + nl;
        uint4 pack = {0u, 0u, 0u, 0u};
        if (wid < N) {             // wave-uniform branch: exec stays full
            int r0 = rowptr[wid], r1 = rowptr[wid + 1];
            float qv = (lane < 8) ? qn[wid * 8 + lane] : 0.f;
            float denom = 0.f;
            float a0 = 0.f, a1 = 0.f, a2 = 0.f, a3 = 0.f;
            float a4 = 0.f, a5 = 0.f, a6 = 0.f, a7 = 0.f;
            int currel = 0;
            float racc = 0.f;

            for (int base = r0; base < r1; base += 64) {
                int s = base + lane;
                int pk = (s < r1) ? csr[s] : 0;
                int src = pk & 0x1FFFF;
                int rel = pk >> 17;
                float qq = __shfl(qv, rel, 64);  // full wave active
                float tv = 0.f;
                if (s < r1) {
                    float v = qq + kn[src * 8 + rel];
                    v = (v >= 0.f) ? v : 0.2f * v;
                    tv = __expf(v);
                }
                float ts = tv;
#pragma unroll
                for (int off = 32; off > 0; off >>= 1) ts += __shfl_xor(ts, off, 64);
                denom += ts;

                int cnt = min(64, r1 - base);
                int tvi = (int)__float_as_uint(tv);
                for (int j = 0; j < cnt; j += 16) {
                    unsigned p[16];
                    float t[16];
#pragma unroll
                    for (int u = 0; u < 16; u++) {
                        p[u] = (unsigned)__builtin_amdgcn_readlane(pk, j + u);
                        t[u] = __uint_as_float(
                            (unsigned)__builtin_amdgcn_readlane(tvi, j + u));
                    }
                    unsigned xu[16];
#pragma unroll
                    for (int u = 0; u < 16; u++)
                        xu[u] = (unsigned)xb[(size_t)(p[u] & 0x1FFFF) * 64 + lane];
#pragma unroll
                    for (int u = 0; u < 16; u++) {
                        int rl = (int)(p[u] >> 17);  // SGPR
                        if (rl != currel) {          // uniform scalar branch
                            switch (currel) {
                                case 0: a0 += racc; break;
                                case 1: a1 += racc; break;
                                case 2: a2 += racc; break;
                                case 3: a3 += racc; break;
                                case 4: a4 += racc; break;
                                case 5: a5 += racc; break;
                                case 6: a6 += racc; break;
                                case 7: a7 += racc; break;
                            }
                            currel = rl;
                            racc = 0.f;
                        }
                        racc += t[u] * __uint_as_float(xu[u] << 16);
                    }
                }
            }
            switch (currel) {
                case 0: a0 += racc; break;
                case 1: a1 += racc; break;
                case 2: a2 += racc; break;
                case 3: a3 += racc; break;
                case 4: a4 += racc; break;
                case 5: a5 += racc; break;
                case 6: a6 += racc; break;
                case 7: a7 += racc; break;
            }
            float inv = 1.f / (denom + 1e-16f);
            float av[8] = {a0, a1, a2, a3, a4, a5, a6, a7};
            unsigned short u[8];
#pragma unroll
            for (int r = 0; r < 8; r++) {
                __hip_bfloat16 b = __float2bfloat16(av[r] * inv);
                u[r] = *(unsigned short*)&b;
            }
            pack.x = (unsigned)u[0] | ((unsigned)u[1] << 16);
            pack.y = (unsigned)u[2] | ((unsigned)u[3] << 16);
            pack.z = (unsigned)u[4] | ((unsigned)u[5] << 16);
            pack.w = (unsigned)u[6] | ((unsigned)u[7] << 16);
        }
        *(uint4*)&zt[nl * ZSTR + lane * 8] = pack;  // zero for tail rows
    }
    __syncthreads();

    // ---- phase 2: out-tile GEMM from LDS ----
    int quad = lane >> 4;
    int l15 = lane & 15;
    int nt = wv;  // 16-col tile per wave
    if (nt * 16 < OUT) {
        const short* wh = (const short*)wthi;
        const short* wl = (const short*)wtlo;
        v4f acc = {0.f, 0.f, 0.f, 0.f};
#pragma unroll
        for (int k0 = 0; k0 < 512; k0 += 32) {
            int koff = k0 + quad * 8;
            v8s A = *(const v8s*)&zt[l15 * ZSTR + koff];
            v8s bh = *(const v8s*)(wh + (size_t)(nt * 16 + l15) * 512 + koff);
            v8s bl = *(const v8s*)(wl + (size_t)(nt * 16 + l15) * 512 + koff);
            acc = __builtin_amdgcn_mfma_f32_16x16x32_bf16(A, bh, acc, 0, 0, 0);
            acc = __builtin_amdgcn_mfma_f32_16x16x32_bf16(A, bl, acc, 0, 0, 0);
        }
        float bcol = bias[nt * 16 + l15];
#pragma unroll
        for (int g = 0; g < 4; g++) {
            int row = nb0 + quad * 4 + g;
            if (row < N) {
                float o = acc[g] + bcol;
                if (RELU) o = fmaxf(o, 0.f);
                xout[(size_t)row * OUT + nt * 16 + l15] = o;
            }
        }
    }
}

// ---------------- host launch ----------------

extern "C" void kernel_launch(void* const* d_in, const int* in_sizes, int n_in,
                              void* d_out, int out_size, void* d_ws, size_t ws_size,
                              hipStream_t stream) {
    const float* x   = (const float*)d_in[0];
    const int*   ei  = (const int*)d_in[1];
    const int*   et  = (const int*)d_in[2];
    const float* W0  = (const float*)d_in[3];
    const float* Q0  = (const float*)d_in[4];
    const float* K0  = (const float*)d_in[5];
    const float* b0  = (const float*)d_in[6];
    const float* W1  = (const float*)d_in[7];
    const float* Q1  = (const float*)d_in[8];
    const float* K1  = (const float*)d_in[9];
    const float* b1  = (const float*)d_in[10];
    float* out = (float*)d_out;

    const int N = in_sizes[0] / 64;
    const int E = in_sizes[2];
    const int* src = ei;
    const int* dst = ei + E;
    const int NB = (N + 255) >> 8;  // <= 512

    char* p = (char*)d_ws;
    auto alloc = [&](size_t bytes) -> void* {
        void* r = (void*)p;
        p += ((bytes + 255) / 256) * 256;
        return r;
    };
    int* rowptr   = (int*)alloc((size_t)(N + 1) * 4);
    int* bcount   = (int*)alloc(513 * 4);
    int* bstart   = (int*)alloc(513 * 4);
    int* gcur     = (int*)alloc(513 * 4);
    unsigned* ebuf = (unsigned*)alloc((size_t)E * 4);
    int* csr      = (int*)alloc((size_t)E * 4);
    float* wq     = (float*)alloc(8 * 64 * 4);
    float* wk     = (float*)alloc(8 * 64 * 4);
    float* qn     = (float*)alloc((size_t)N * 8 * 4);
    float* kn     = (float*)alloc((size_t)N * 8 * 4);
    __hip_bfloat16* wthi = (__hip_bfloat16*)alloc((size_t)64 * 512 * 2);
    __hip_bfloat16* wtlo = (__hip_bfloat16*)alloc((size_t)64 * 512 * 2);
    float* h      = (float*)alloc((size_t)N * 64 * 4);
    unsigned short* xbb = (unsigned short*)alloc((size_t)N * 64 * 2);  // bf16 gather table

    // --- CSR build (bucketed counting sort; shared by both layers) ---
    int nchunks = (E + CSR_CHUNK - 1) / CSR_CHUNK;
    hipMemsetAsync(bcount, 0, (size_t)NB * 4, stream);
    k_bhist<<<nchunks, 256, 0, stream>>>(dst, bcount, E, NB);
    k_bscan<<<1, 512, 0, stream>>>(bcount, bstart, gcur, rowptr, NB, N, E);
    k_bscatter<<<nchunks, 256, 0, stream>>>(src, dst, et, gcur, ebuf, E, NB);
    k_bsort<<<NB, 256, 0, stream>>>(ebuf, bstart, rowptr, csr, N);

    int nfb = (N + 15) / 16;
    int nqkb = (N + 63) / 64;

    // --- layer 0: 64 -> 64, relu ---
    k_wqk<<<2, 256, 0, stream>>>(W0, Q0, K0, wq, wk, 64);
    k_qk2<<<nqkb, 256, 0, stream>>>(x, wq, wk, qn, kn, xbb, N);
    k_wt2<<<(8 * 64 * 64 + 255) / 256, 256, 0, stream>>>(W0, wthi, wtlo, 64, 8 * 64 * 64);
    k_fused<64, true><<<nfb, 256, 0, stream>>>(rowptr, csr, qn, kn, xbb,
                                               wthi, wtlo, b0, h, N);

    // --- layer 1: 64 -> 32, no relu ---
    k_wqk<<<2, 256, 0, stream>>>(W1, Q1, K1, wq, wk, 32);
    k_qk2<<<nqkb, 256, 0, stream>>>(h, wq, wk, qn, kn, xbb, N);
    k_wt2<<<(8 * 64 * 32 + 255) / 256, 256, 0, stream>>>(W1, wthi, wtlo, 32, 8 * 64 * 32);
    k_fused<32, false><<<nfb, 256, 0, stream>>>(rowptr, csr, qn, kn, xbb,
                                                wthi, wtlo, b1, out, N);
}